// Round 1
// baseline (567.968 us; speedup 1.0000x reference)
//
#include <hip/hip_runtime.h>
#include <stdint.h>

// Problem constants (fixed by setup_inputs)
#define B_ 64
#define C_ 256
#define H_ 56
#define W_ 56
#define HM 50              // H - (BLOCK_SIZE-1)
#define WM 50
#define NPLANES (B_ * C_)          // 16384
#define PLANE_IN (HM * WM)         // 2500
#define PLANE_OUT (H_ * W_)        // 3136
#define NTOT (NPLANES * PLANE_OUT) // 51,380,224

__global__ void zero_counter(unsigned int* cnt) {
    if (threadIdx.x == 0) *cnt = 0u;
}

// One block per (b,c) plane. Builds the dilated-keep bitmask (56 rows x 56 bits)
// and accumulates the global count of kept (mask==1) elements.
__global__ __launch_bounds__(256) void dilate_kernel(
        const float* __restrict__ u,
        const float* __restrict__ gamma,
        unsigned long long* __restrict__ mask_out,   // [NPLANES * H_]
        unsigned int* __restrict__ counter) {
    __shared__ unsigned char seed[PLANE_IN];   // 2500 B
    __shared__ unsigned long long hdil[HM];    // 400 B

    const int plane = blockIdx.x;
    const int tid   = threadIdx.x;
    const float g   = gamma[0];

    // Coalesced float4 load of the u plane (2500 floats = 625 float4, 16B-aligned
    // since 2500*4 = 10000 = 625*16 bytes per plane).
    const float4* up = (const float4*)(u + (size_t)plane * PLANE_IN);
    for (int i = tid; i < PLANE_IN / 4; i += 256) {
        float4 v = up[i];
        seed[4 * i + 0] = (unsigned char)(v.x < g);
        seed[4 * i + 1] = (unsigned char)(v.y < g);
        seed[4 * i + 2] = (unsigned char)(v.z < g);
        seed[4 * i + 3] = (unsigned char)(v.w < g);
    }
    __syncthreads();

    // Per-row bitmask + horizontal dilation (window 7 => OR of shifts 0..6).
    if (tid < HM) {
        const unsigned char* row = &seed[tid * WM];
        unsigned long long bits = 0ull;
        #pragma unroll
        for (int w = 0; w < WM; ++w)
            bits |= (unsigned long long)row[w] << w;
        // log-step smear: {0,1} -> {0..3} -> {0..6}
        unsigned long long h = bits | (bits << 1);
        h |= h << 2;
        h |= h << 3;
        hdil[tid] = h;   // bits 0..55 valid (49+6)
    }
    __syncthreads();

    // Vertical dilation (rows h-6..h clipped to [0,HM)), invert -> keep bits,
    // store, and count kept elements.
    unsigned int zcnt = 0;
    if (tid < H_) {
        int r0 = tid - 6; if (r0 < 0) r0 = 0;
        int r1 = tid;     if (r1 > HM - 1) r1 = HM - 1;
        unsigned long long v = 0ull;
        for (int r = r0; r <= r1; ++r) v |= hdil[r];
        unsigned long long keep = (~v) & ((1ULL << W_) - 1ULL);
        mask_out[(size_t)plane * H_ + tid] = keep;
        zcnt = (unsigned int)__popcll(keep);
    }
    // Wave-0 reduction (threads 0..63 are exactly wave 0), one atomic per block.
    if (tid < 64) {
        #pragma unroll
        for (int off = 32; off > 0; off >>= 1)
            zcnt += __shfl_down(zcnt, off, 64);
        if (tid == 0) atomicAdd(counter, zcnt);
    }
}

// Elementwise: out = x * scale * keep_bit, float4-vectorized.
__global__ __launch_bounds__(256) void apply_kernel(
        const float* __restrict__ x,
        const unsigned long long* __restrict__ mask,
        const unsigned int* __restrict__ counter,
        float* __restrict__ out) {
    __shared__ float s_scale;
    if (threadIdx.x == 0) {
        unsigned int ones = *counter;
        s_scale = (float)NTOT / (float)ones;
    }
    __syncthreads();
    const float scale = s_scale;

    int idx4 = blockIdx.x * 256 + threadIdx.x;  // grid sized exactly NTOT/4/256
    int e    = idx4 * 4;                        // < 2^31
    int plane = e / PLANE_OUT;
    int rem   = e - plane * PLANE_OUT;
    int h     = rem / W_;
    int w     = rem - h * W_;                   // multiple of 4

    unsigned long long bits = mask[(size_t)plane * H_ + h] >> w;
    float4 v = ((const float4*)x)[idx4];
    float4 o;
    o.x = (bits & 1ull) ? v.x * scale : 0.0f;
    o.y = (bits & 2ull) ? v.y * scale : 0.0f;
    o.z = (bits & 4ull) ? v.z * scale : 0.0f;
    o.w = (bits & 8ull) ? v.w * scale : 0.0f;
    ((float4*)out)[idx4] = o;
}

extern "C" void kernel_launch(void* const* d_in, const int* in_sizes, int n_in,
                              void* d_out, int out_size, void* d_ws, size_t ws_size,
                              hipStream_t stream) {
    const float* x     = (const float*)d_in[0];
    const float* u     = (const float*)d_in[1];
    const float* gamma = (const float*)d_in[2];
    float* out = (float*)d_out;

    // Workspace layout: [0,4) counter; [256, 256 + NPLANES*H_*8) bit-packed keep mask.
    unsigned int* counter = (unsigned int*)d_ws;
    unsigned long long* mask = (unsigned long long*)((char*)d_ws + 256);

    zero_counter<<<1, 64, 0, stream>>>(counter);
    dilate_kernel<<<NPLANES, 256, 0, stream>>>(u, gamma, mask, counter);
    apply_kernel<<<NTOT / (4 * 256), 256, 0, stream>>>(x, mask, counter, out);
}